// Round 2
// baseline (467.832 us; speedup 1.0000x reference)
//
#include <hip/hip_runtime.h>
#include <hip/hip_bf16.h>

// Problem constants
// x:(4096,8,1024) f32, U:(8,1048576,4) f32, V:(4,1048576,4) f32,
// scale:(8,1), biasq:(8,1), bias:(8,1024)  -> out:(4096,8,1024) f32
// D = 1024*1024 = 2^20, B=4096, N=8, K=4, BW=4, T=1.0

typedef __attribute__((ext_vector_type(8))) short short8;
typedef __attribute__((ext_vector_type(4))) float f32x4;
typedef __attribute__((ext_vector_type(4))) unsigned short ushort4v;
typedef __attribute__((ext_vector_type(2))) unsigned int uint2v;

__device__ __forceinline__ unsigned short f2bf(float f) {
  union { float f; unsigned u; } a; a.f = f;
  unsigned u = a.u;
  u += 0x7fffu + ((u >> 16) & 1u);   // RNE; inputs are finite
  return (unsigned short)(u >> 16);
}

__device__ __forceinline__ unsigned pk2(float a, float b) {
  __hip_bfloat162 h = __float22bfloat162_rn(make_float2(a, b));
  union { __hip_bfloat162 h; unsigned u; } c; c.h = h;
  return c.u;
}

// ---------------------------------------------------------------------------
// Kernel 1: weight synthesis -> W^T bf16: Wt[n][l=d2][d1]
// This round: precise divide -> v_rcp_f32 (output is bf16-rounded; 1-ULP rcp
// error invisible). Otherwise unchanged.
// ---------------------------------------------------------------------------
__global__ __launch_bounds__(256) void wgen_kernel(
    const float4* __restrict__ U4, const float4* __restrict__ V4,
    const float* __restrict__ scale, const float* __restrict__ biasq,
    unsigned short* __restrict__ Wt) {
  __shared__ float tiles[8][32][33];
  const int t = threadIdx.x;
  const int d1_0 = blockIdx.x * 32;
  const int d2_0 = blockIdx.y * 32;
#pragma unroll
  for (int i = 0; i < 4; i++) {
    const int e = t + 256 * i;
    const int r = e >> 5, c = e & 31;          // r: d1 offset, c: d2 offset
    const size_t d = (size_t)(d1_0 + r) * 1024 + (size_t)(d2_0 + c);
    float4 u[8];
#pragma unroll
    for (int nn = 0; nn < 8; nn++) u[nn] = U4[((size_t)nn << 20) + d];
    float integ[8];
#pragma unroll
    for (int nn = 0; nn < 8; nn++) integ[nn] = 0.f;
#pragma unroll
    for (int b = 0; b < 4; b++) {
      const float4 v = V4[((size_t)b << 20) + d];
      const float pw = (float)(1 << b);
#pragma unroll
      for (int nn = 0; nn < 8; nn++) {
        float th = u[nn].x * v.x + u[nn].y * v.y + u[nn].z * v.z + u[nn].w * v.w;
        th = fminf(10.f, fmaxf(-10.f, th));
        integ[nn] += pw * __builtin_amdgcn_rcpf(1.f + __expf(-th));
      }
    }
#pragma unroll
    for (int nn = 0; nn < 8; nn++) tiles[nn][r][c] = integ[nn];
  }
  __syncthreads();
  const int orow = t >> 3;                     // d2 offset 0..31
  const int oc0 = (t & 7) * 4;                 // d1 offset (x4)
#pragma unroll
  for (int nn = 0; nn < 8; nn++) {
    const float sc = scale[nn], bq = biasq[nn];
    ushort4v o;
    o.x = f2bf(sc * (tiles[nn][oc0 + 0][orow] - bq - 16.f));
    o.y = f2bf(sc * (tiles[nn][oc0 + 1][orow] - bq - 16.f));
    o.z = f2bf(sc * (tiles[nn][oc0 + 2][orow] - bq - 16.f));
    o.w = f2bf(sc * (tiles[nn][oc0 + 3][orow] - bq - 16.f));
    *(ushort4v*)(Wt + ((size_t)nn << 20) + (size_t)(d2_0 + orow) * 1024 +
                 (size_t)(d1_0 + oc0)) = o;
  }
}

// ---------------------------------------------------------------------------
// Kernel 1b: xcast — X fp32 -> Xb bf16, same [4096][8][1024] layout.
// Pure streaming: float4 load -> cvt_pk -> 8B store. ~192 MiB traffic.
// Paying this ~30 us ONCE removes the per-K-step fp32-load->cvt->ds_write
// serial chain from the gemm (which also redid the cvt 8x per A panel).
// ---------------------------------------------------------------------------
__global__ __launch_bounds__(256) void xcast_kernel(
    const float4* __restrict__ X4, uint2v* __restrict__ Xb) {
  const size_t total = (size_t)4096 * 8 * 1024 / 4;  // 8388608 float4s
  const size_t stride = (size_t)gridDim.x * 256;
  for (size_t i = (size_t)blockIdx.x * 256 + threadIdx.x; i < total; i += stride) {
    const float4 v = X4[i];
    uint2v p;
    p.x = pk2(v.x, v.y);
    p.y = pk2(v.z, v.w);
    Xb[i] = p;
  }
}

// ---------------------------------------------------------------------------
// Kernel 2: batched bf16 GEMM — pure R2/m97 structure (the config whose gemm
// dispatch was verified at 130 us): BK=64, 128x128 tile, 4 waves 2x2, 4x4
// mfma_f32_16x16x32_bf16, BOTH A and B staged via global_load_lds with
// pre-swizzled global chunk addressing (XOR chunk ^ (row&7)); LDS linear.
// T1 XCD-aware group swizzle kept (bijective; groups sharing an A-panel land
// on one XCD within one 64-id window).
// ---------------------------------------------------------------------------
#define AS1(p) ((const __attribute__((address_space(1))) void*)(p))
#define AS3(p) ((__attribute__((address_space(3))) void*)(p))

__global__ __launch_bounds__(256) void gemm_kernel(
    const unsigned short* __restrict__ Xb,   // [4096][8][1024] bf16
    const unsigned short* __restrict__ Wt,   // [8][1024(l)][1024(d1)] bf16
    const float* __restrict__ bias,          // [8][1024]
    float* __restrict__ out) {               // [4096][8][1024]
  __shared__ unsigned short As[128 * 64];    // 16 KiB
  __shared__ unsigned short Bs[128 * 64];    // 16 KiB
  const int t = threadIdx.x;
  const int wv = t >> 6;
  const int ln = t & 63;

  // ---- XCD-aware group swizzle (T1)
  const int lin = (int)(blockIdx.x + 32u * blockIdx.y + 256u * blockIdx.z);
  const int g   = (lin & 7) | ((lin >> 6) << 3);   // group 0..255 = (bm, n)
  const int bnb = (lin >> 3) & 7;                  // bn tile 0..7
  const int n   = g >> 5;                          // ensemble member 0..7
  const int bm0 = (g & 31) * 128;
  const int bn0 = bnb * 128;

  // ---- staging geometry (identical for A and B): 64 lanes cover 8 rows x
  // 8 chunks of 16B; global chunk pre-swizzled by row so LDS is linear.
  const int sr = wv * 8 + (ln >> 3);                 // row 0..31 (+32*r)
  const int sc = (((ln & 7) ^ (sr & 7)) * 8);        // swizzled chunk (shorts)
  const unsigned short* ag =
      Xb + ((size_t)(bm0 + sr) * 8 + (size_t)n) * 1024 + sc;   // row stride 8192
  const unsigned short* bg =
      Wt + ((size_t)n << 20) + (size_t)(bn0 + sr) * 1024 + sc; // row stride 1024
  unsigned short* lA = As + wv * 512;                // wave-uniform LDS base
  unsigned short* lB = Bs + wv * 512;

  // ---- fragment-read geometry
  const int wm = wv >> 1, wn = wv & 1;
  const int lm = ln & 15;
  const int cq = ln >> 4;                            // k-quarter 0..3
  const int sw = lm & 7;                             // row swizzle key
  const unsigned short* a_rd = As + (wm * 64 + lm) * 64;
  const unsigned short* b_rd = Bs + (wn * 64 + lm) * 64;

  f32x4 acc[4][4];
#pragma unroll
  for (int i = 0; i < 4; i++)
#pragma unroll
    for (int j = 0; j < 4; j++) acc[i][j] = (f32x4){0.f, 0.f, 0.f, 0.f};

  for (int k0 = 0; k0 < 1024; k0 += 64) {
    // A + B: async global->LDS, 8 x 16B per thread, no VALU staging
#pragma unroll
    for (int r = 0; r < 4; r++)
      __builtin_amdgcn_global_load_lds(AS1(ag + (size_t)(32 * r) * 8192 + k0),
                                       AS3(lA + r * 2048), 16, 0, 0);
#pragma unroll
    for (int r = 0; r < 4; r++)
      __builtin_amdgcn_global_load_lds(AS1(bg + (size_t)(32 * r) * 1024 + k0),
                                       AS3(lB + r * 2048), 16, 0, 0);
    __syncthreads();
#pragma unroll
    for (int half = 0; half < 2; half++) {
      const int off = ((half * 4 + cq) ^ sw) * 8;    // swizzled 16B chunk
      short8 af[4], bfr[4];
#pragma unroll
      for (int i = 0; i < 4; i++) af[i] = *(const short8*)(a_rd + i * 1024 + off);
#pragma unroll
      for (int j = 0; j < 4; j++) bfr[j] = *(const short8*)(b_rd + j * 1024 + off);
#pragma unroll
      for (int i = 0; i < 4; i++)
#pragma unroll
        for (int j = 0; j < 4; j++)
          acc[i][j] = __builtin_amdgcn_mfma_f32_16x16x32_bf16(af[i], bfr[j],
                                                              acc[i][j], 0, 0, 0);
    }
    __syncthreads();
  }

  // Epilogue: C/D layout col=lane&15, row=(lane>>4)*4+reg  [m89/m91]
  const int q = ln >> 4;
  const int row0 = bm0 + wm * 64 + q * 4;
  const int col0 = bn0 + wn * 64 + lm;
  float bv[4];
#pragma unroll
  for (int j = 0; j < 4; j++) bv[j] = bias[n * 1024 + col0 + j * 16];
#pragma unroll
  for (int i = 0; i < 4; i++) {
#pragma unroll
    for (int r = 0; r < 4; r++) {
      const int row = row0 + i * 16 + r;
      float* op = out + ((size_t)row * 8 + (size_t)n) * 1024;
#pragma unroll
      for (int j = 0; j < 4; j++) op[col0 + j * 16] = acc[i][j][r] + bv[j];
    }
  }
}

// ---------------------------------------------------------------------------
extern "C" void kernel_launch(void* const* d_in, const int* in_sizes, int n_in,
                              void* d_out, int out_size, void* d_ws, size_t ws_size,
                              hipStream_t stream) {
  const float* x     = (const float*)d_in[0];
  const float* U     = (const float*)d_in[1];
  const float* V     = (const float*)d_in[2];
  const float* scale = (const float*)d_in[3];
  const float* biasq = (const float*)d_in[4];
  const float* bias  = (const float*)d_in[5];
  float* out = (float*)d_out;

  // workspace: Wt bf16 [8][1024][1024] = 16 MiB, Xb bf16 [4096][8][1024] = 64 MiB
  unsigned short* Wt = (unsigned short*)d_ws;
  unsigned short* Xb = (unsigned short*)d_ws + (size_t)8 * 1024 * 1024;

  wgen_kernel<<<dim3(32, 32), 256, 0, stream>>>((const float4*)U, (const float4*)V,
                                                scale, biasq, Wt);
  xcast_kernel<<<dim3(2048), 256, 0, stream>>>((const float4*)x, (uint2v*)Xb);
  gemm_kernel<<<dim3(32, 8, 8), 256, 0, stream>>>(Xb, Wt, bias, out);
}